// Round 1
// baseline (141.944 us; speedup 1.0000x reference)
//
#include <hip/hip_runtime.h>
#include <math.h>
#include <limits.h>

namespace {
constexpr int G = 16;    // num_graphs
constexpr int N = 2048;  // num_nodes
constexpr int K = 16;    // k_neighs
constexpr int C = 20;    // candidates kept per side (K + self-exclusion + tie slack)
}

// Per graph: indices of the C largest and C smallest t values,
// ordered by (value, then lower index) — matches lax.top_k tie-break.
__global__ void topk_kernel(const float* __restrict__ emb_t,
                            int* __restrict__ maxidx,
                            int* __restrict__ minidx) {
    __shared__ float sa[N];
    __shared__ float sb[N];
    const int g = blockIdx.x;
    const int lane = threadIdx.x;  // block = 64 = one wave
    const float* t = emb_t + (size_t)g * N;

    for (int m = 0; m < N / 64; ++m) {
        const float v = t[lane + 64 * m];
        sa[lane + 64 * m] = v;
        sb[lane + 64 * m] = v;
    }
    __syncthreads();

    // C passes of wave-wide argmax (prefer larger val, then lower index)
    for (int p = 0; p < C; ++p) {
        float bv = -INFINITY; int bi = INT_MAX;
        for (int m = 0; m < N / 64; ++m) {
            const int idx = lane + 64 * m;
            const float v = sa[idx];
            if (v > bv || (v == bv && idx < bi)) { bv = v; bi = idx; }
        }
        #pragma unroll
        for (int off = 32; off >= 1; off >>= 1) {
            const float ov = __shfl_xor(bv, off);
            const int   oi = __shfl_xor(bi, off);
            if (ov > bv || (ov == bv && oi < bi)) { bv = ov; bi = oi; }
        }
        if (lane == 0) { maxidx[g * C + p] = bi; sa[bi] = -INFINITY; }
        __syncthreads();
    }

    // C passes of wave-wide argmin (prefer smaller val, then lower index)
    for (int p = 0; p < C; ++p) {
        float bv = INFINITY; int bi = INT_MAX;
        for (int m = 0; m < N / 64; ++m) {
            const int idx = lane + 64 * m;
            const float v = sb[idx];
            if (v < bv || (v == bv && idx < bi)) { bv = v; bi = idx; }
        }
        #pragma unroll
        for (int off = 32; off >= 1; off >>= 1) {
            const float ov = __shfl_xor(bv, off);
            const int   oi = __shfl_xor(bi, off);
            if (ov < bv || (ov == bv && oi < bi)) { bv = ov; bi = oi; }
        }
        if (lane == 0) { minidx[g * C + p] = bi; sb[bi] = INFINITY; }
        __syncthreads();
    }
}

// One block (1 wave) per output row: zero 2048 f32 with float4 stores,
// then mark the exact top-K indices with 1.0f.
__global__ void fill_kernel(const float* __restrict__ emb_s,
                            const float* __restrict__ emb_t,
                            const int* __restrict__ maxidx,
                            const int* __restrict__ minidx,
                            float* __restrict__ out) {
    const int bid = blockIdx.x;          // 0 .. G*N-1
    const int g = bid >> 11;             // N = 2048
    const int i = bid & (N - 1);
    const int lane = threadIdx.x;        // 0..63
    float* row = out + (size_t)bid * N;

    const float4 z = make_float4(0.f, 0.f, 0.f, 0.f);
    #pragma unroll
    for (int w = 0; w < N / (64 * 4); ++w) {
        reinterpret_cast<float4*>(row)[lane + 64 * w] = z;
    }

    __syncthreads();  // zeros visible before scattering ones into same row

    const float s = emb_s[g * N + i];

    if (s != 0.0f) {
        // candidate (product, index) per lane; lanes >= C hold sentinels
        const int* list = (s > 0.0f) ? (maxidx + g * C) : (minidx + g * C);
        float p = -INFINITY;
        int idx = INT_MAX;
        if (lane < C) {
            idx = list[lane];
            p = s * emb_t[g * N + idx];   // same rounding as reference adj
            if (idx == i) { p = -INFINITY; idx = INT_MAX; }  // exclude diagonal
        }
        // exact top_k rank among the C candidates: (value desc, index asc)
        int rank = 0;
        for (int c = 0; c < C; ++c) {
            const float pc = __shfl(p, c);
            const int   ic = __shfl(idx, c);
            if (pc > p || (pc == p && ic < idx)) ++rank;
        }
        if (lane < C && rank < K && idx != INT_MAX) row[idx] = 1.0f;
    } else {
        // s == 0: all products are +/-0.0 (ties) -> lowest K indices, skip i
        if (lane < K) {
            const int pos = (i < K + 1) ? i : (K + 1);
            const int sel = (lane < pos) ? lane : lane + 1;
            row[sel] = 1.0f;
        }
    }
}

extern "C" void kernel_launch(void* const* d_in, const int* in_sizes, int n_in,
                              void* d_out, int out_size, void* d_ws, size_t ws_size,
                              hipStream_t stream) {
    const float* emb_s = (const float*)d_in[0];   // (G, N, 1) f32
    const float* emb_t = (const float*)d_in[1];   // (G, 1, N) f32
    float* out = (float*)d_out;                   // (G, N, N) f32

    int* maxidx = (int*)d_ws;                     // G*C ints
    int* minidx = maxidx + G * C;                 // G*C ints

    topk_kernel<<<G, 64, 0, stream>>>(emb_t, maxidx, minidx);
    fill_kernel<<<G * N, 64, 0, stream>>>(emb_s, emb_t, maxidx, minidx, out);
}

// Round 3
// 106.882 us; speedup vs baseline: 1.3280x; 1.3280x over previous
//
#include <hip/hip_runtime.h>
#include <math.h>
#include <limits.h>

namespace {
constexpr int G = 16;    // num_graphs
constexpr int N = 2048;  // num_nodes
constexpr int K = 16;    // k_neighs
constexpr int C = 20;    // candidates per side (K + diag exclusion + tie slack)
constexpr int FILL_BLOCKS = 1024;   // 256 thr = 4 waves each -> 4096 waves, 8 rows/wave
typedef float floatx4 __attribute__((ext_vector_type(4)));  // native vector: OK for nontemporal builtin
}

// 2*G blocks, 1 wave each. Block b: g = b>>1, side = b&1 (0 = largest t, 1 = smallest t).
// Emits candidate indices in exact (value, then lower index) order — lax.top_k tie-break.
__global__ void topk_kernel(const float* __restrict__ emb_t,
                            int* __restrict__ candidx /* [2*G][C] */) {
    __shared__ float sv[N];
    const int g = blockIdx.x >> 1;
    const int side = blockIdx.x & 1;
    const int lane = threadIdx.x;            // 64 = one wave
    const float* t = emb_t + g * N;
    const float sgn = side ? -1.f : 1.f;     // negate for min side -> always argmax

    for (int m = 0; m < N / 64; ++m) sv[lane + 64 * m] = sgn * t[lane + 64 * m];
    __syncthreads();

    for (int p = 0; p < C; ++p) {
        float bv = -INFINITY; int bi = INT_MAX;
        for (int m = 0; m < N / 64; ++m) {
            const int idx = lane + 64 * m;
            const float v = sv[idx];
            if (v > bv || (v == bv && idx < bi)) { bv = v; bi = idx; }
        }
        #pragma unroll
        for (int off = 32; off >= 1; off >>= 1) {
            const float ov = __shfl_xor(bv, off);
            const int   oi = __shfl_xor(bi, off);
            if (ov > bv || (ov == bv && oi < bi)) { bv = ov; bi = oi; }
        }
        if (lane == 0) { candidx[blockIdx.x * C + p] = bi; sv[bi] = -INFINITY; }
        __syncthreads();
    }
}

// Single-pass fill: each wave owns a row; builds a 2048-bit membership mask in
// registers (lane l holds bits for columns [32l, 32l+32)), then streams the row
// out as float4 nontemporal stores — every byte written exactly once.
__global__ __launch_bounds__(256) void fill_kernel(
    const float* __restrict__ emb_s,
    const float* __restrict__ emb_t,
    const int* __restrict__ candidx,
    float* __restrict__ out)
{
    const int lane = threadIdx.x & 63;
    const int wave = threadIdx.x >> 6;
    const int wid = blockIdx.x * 4 + wave;
    const int nwaves = FILL_BLOCKS * 4;

    for (int row = wid; row < G * N; row += nwaves) {
        const int g = row >> 11;             // N = 2048
        const int i = row & (N - 1);
        const float s = emb_s[row];

        int idx = INT_MAX;
        bool sel = false;
        if (s != 0.0f) {
            const int* list = candidx + (g * 2 + (s < 0.0f)) * C;
            float p = -INFINITY;
            if (lane < C) {
                idx = list[lane];
                p = s * emb_t[g * N + idx];          // same rounding as reference adj
                if (idx == i) { p = -INFINITY; idx = INT_MAX; }  // exclude diagonal
            }
            // exact top_k rank among candidates: (value desc, index asc)
            int rank = 0;
            for (int c = 0; c < C; ++c) {
                const float pc = __shfl(p, c);
                const int   ic = __shfl(idx, c);
                if (pc > p || (pc == p && ic < idx)) ++rank;
            }
            sel = (lane < C) && (rank < K) && (idx != INT_MAX);
        } else {
            // s == +/-0: all products are +/-0 (compare-equal) -> lowest K indices, skip i
            if (lane < K) {
                const int pos = (i < K + 1) ? i : (K + 1);
                idx = (lane < pos) ? lane : lane + 1;
                sel = true;
            }
        }

        // Build the row bitmask: lane l owns one 32-bit word.
        unsigned word = 0;
        for (int c = 0; c < C; ++c) {
            const int ic = __shfl(idx, c);
            const int sc = __shfl((int)sel, c);
            if (sc && (ic >> 5) == lane) word |= 1u << (ic & 31);
        }

        // Stream the row: 8 chunks x 256 floats; chunk c, lane l -> cols c*256+4l..+3.
        float* rowp = out + (size_t)row * N;
        #pragma unroll
        for (int c = 0; c < 8; ++c) {
            const unsigned w = (unsigned)__shfl((int)word, c * 8 + (lane >> 3));
            const int b0 = (lane & 7) * 4;
            floatx4 v;
            v.x = ((w >> (b0 + 0)) & 1u) ? 1.f : 0.f;
            v.y = ((w >> (b0 + 1)) & 1u) ? 1.f : 0.f;
            v.z = ((w >> (b0 + 2)) & 1u) ? 1.f : 0.f;
            v.w = ((w >> (b0 + 3)) & 1u) ? 1.f : 0.f;
            __builtin_nontemporal_store(v, reinterpret_cast<floatx4*>(rowp) + c * 64 + lane);
        }
    }
}

extern "C" void kernel_launch(void* const* d_in, const int* in_sizes, int n_in,
                              void* d_out, int out_size, void* d_ws, size_t ws_size,
                              hipStream_t stream) {
    const float* emb_s = (const float*)d_in[0];   // (G, N, 1) f32
    const float* emb_t = (const float*)d_in[1];   // (G, 1, N) f32
    float* out = (float*)d_out;                   // (G, N, N) f32

    int* candidx = (int*)d_ws;                    // [2*G][C] ints

    topk_kernel<<<2 * G, 64, 0, stream>>>(emb_t, candidx);
    fill_kernel<<<FILL_BLOCKS, 256, 0, stream>>>(emb_s, emb_t, candidx, out);
}